// Round 11
// baseline (149.644 us; speedup 1.0000x reference)
//
#include <hip/hip_runtime.h>
#include <stdint.h>
#include <math.h>

// PhysicsForwardModel: B=2, Nz=Nx=128, Ly=Lx=512.
// out[b,t,l] = (1/3) * sum_j Cy[j,l] * sum_k cos(F[k,j]*t) * a[k] * (Cy[:,:128] x[b] Cy[:,128:256]^T)[k,j]
//              + std_b * N(0,1)  (JAX threefry key=42, partitionable counters, XLA erfinv)
// Cy/F recomputed on the fly (pow2 scales exact -> op order matches ref f32 sequence).
// R11: k-split grid (j, khalf) doubles occupancy vs R10 (R10's 2 waves/SIMD stalled
// the cos chains); keeps R10's 1-ds_read_b128-per-2k LDS ratio. stageC sums halves.

#define HALF_N 262144  // 512*512 per-batch elements
#define PI_F 3.14159274101257324f

// ws layout (floats): Vt [0..1048576) = 2 half-k partials of [j][b][t];
//                     partial [1048576..1050624)

__device__ __forceinline__ uint32_t rotl32(uint32_t v, int r) {
  return (v << r) | (v >> (32 - r));
}

// XLA ErfInv32 (Giles) -- matches reference's lax.erf_inv
__device__ __forceinline__ float erfinv_xla(float x) {
  float w = -log1pf(__fmul_rn(-x, x));
  float p;
  if (w < 5.0f) {
    w = w - 2.5f;
    p = 2.81022636e-08f;
    p = fmaf(p, w, 3.43273939e-07f);
    p = fmaf(p, w, -3.5233877e-06f);
    p = fmaf(p, w, -4.39150654e-06f);
    p = fmaf(p, w, 0.00021858087f);
    p = fmaf(p, w, -0.00125372503f);
    p = fmaf(p, w, -0.00417768164f);
    p = fmaf(p, w, 0.246640727f);
    p = fmaf(p, w, 1.50140941f);
  } else {
    w = __fsqrt_rn(w) - 3.0f;
    p = -0.000200214257f;
    p = fmaf(p, w, 0.000100950558f);
    p = fmaf(p, w, 0.00134934322f);
    p = fmaf(p, w, -0.00367342844f);
    p = fmaf(p, w, 0.00573950773f);
    p = fmaf(p, w, -0.0076224613f);
    p = fmaf(p, w, 0.00943887047f);
    p = fmaf(p, w, 1.00167406f);
    p = fmaf(p, w, 2.83297682f);
  }
  return p * x;
}

// Cy[k,n] = sc(k) * 2 * cos(pi*(2n+1)*k/1024), n2p1 = (float)(2n+1) exact
__device__ __forceinline__ float cy_elem(float n2p1, float kf, float sc) {
  float t1 = __fmul_rn(PI_F, n2p1);
  float arg = __fmul_rn(t1, kf) * (1.0f / 1024.0f);
  return __fmul_rn(sc, __fmul_rn(2.0f, __cosf(arg)));
}

// fusedB, block = (j, khalf) (grid 1024, 256 threads):
//   A  (tid<128): cyl[jj] = Cy[j,128+jj]
//   A2 (tid<256): us[b*128+i] = sum_jj x[b,i,jj]*cyl[jj]
//   B  (lane=k=kbase+tid): msf[2*tid+b] = a[k] * sum_i Cy[k,i]*us[b,i]
//   C  (2 t's/lane): Vt[kh][j,b,t] = sum_{k in half} cos(F(k)*t)*msf, F on the fly
__global__ __launch_bounds__(256) void stageB_kernel(const float* __restrict__ x,
                                                     float* __restrict__ Vt) {
  __shared__ float cyl[128];
  __shared__ float us[256];
  __shared__ float msf[512];
  int j = blockIdx.x >> 1;
  int kh = blockIdx.x & 1;
  int kbase = kh << 8;
  int tid = threadIdx.x;
  float jf = (float)j;
  const float s0c = 1.0f / __fsqrt_rn(2048.0f);
  if (tid < 128) {
    float scj = (j == 0) ? s0c : 0.03125f;
    cyl[tid] = cy_elem((float)(2 * (128 + tid) + 1), jf, scj);
  }
  __syncthreads();
  {
    int b = tid >> 7, i = tid & 127;
    const float* xr = x + (b * 128 + i) * 128;
    float accA = 0.0f, accB = 0.0f;
    for (int jj = 0; jj < 128; jj += 8) {
      float4 xa = *(const float4*)&xr[jj];
      float4 xb = *(const float4*)&xr[jj + 4];
      float4 ca = *(const float4*)&cyl[jj];
      float4 cb = *(const float4*)&cyl[jj + 4];
      accA = fmaf(xa.x, ca.x, accA); accB = fmaf(xa.y, ca.y, accB);
      accA = fmaf(xa.z, ca.z, accA); accB = fmaf(xa.w, ca.w, accB);
      accA = fmaf(xb.x, cb.x, accA); accB = fmaf(xb.y, cb.y, accB);
      accA = fmaf(xb.z, cb.z, accA); accB = fmaf(xb.w, cb.w, accB);
    }
    us[tid] = accA + accB;
  }
  __syncthreads();
  {
    int k = kbase + tid;
    float kf = (float)k;
    float sc = (k == 0) ? s0c : 0.03125f;
    float a = cy_elem(1.0f, kf, sc);  // i=0: a[k] = Cy[k,0]
    float acc0 = __fmul_rn(a, us[0]);
    float acc1 = __fmul_rn(a, us[128]);
    float accA0 = 0.f, accA1 = 0.f;
    {
      float c1 = cy_elem(3.0f, kf, sc);
      float c2 = cy_elem(5.0f, kf, sc);
      float c3 = cy_elem(7.0f, kf, sc);
      acc0 = fmaf(c1, us[1], acc0);   acc1 = fmaf(c1, us[129], acc1);
      accA0 = fmaf(c2, us[2], accA0); accA1 = fmaf(c2, us[130], accA1);
      acc0 = fmaf(c3, us[3], acc0);   acc1 = fmaf(c3, us[131], acc1);
    }
    for (int i = 4; i < 128; i += 4) {
      float b0 = (float)(2 * i + 1);
      float c0 = cy_elem(b0, kf, sc);
      float c1 = cy_elem(__fadd_rn(b0, 2.0f), kf, sc);
      float c2 = cy_elem(__fadd_rn(b0, 4.0f), kf, sc);
      float c3 = cy_elem(__fadd_rn(b0, 6.0f), kf, sc);
      float4 u0 = *(const float4*)&us[i];
      float4 u1 = *(const float4*)&us[128 + i];
      acc0 = fmaf(c0, u0.x, acc0);   acc1 = fmaf(c0, u1.x, acc1);
      accA0 = fmaf(c1, u0.y, accA0); accA1 = fmaf(c1, u1.y, accA1);
      acc0 = fmaf(c2, u0.z, acc0);   acc1 = fmaf(c2, u1.z, acc1);
      accA0 = fmaf(c3, u0.w, accA0); accA1 = fmaf(c3, u1.w, accA1);
    }
    acc0 += accA0;
    acc1 += accA1;
    msf[2 * tid] = __fmul_rn(a, acc0);
    msf[2 * tid + 1] = __fmul_rn(a, acc1);
  }
  __syncthreads();
  // phase C: 2 t's per lane over this block's 256 k's; F recomputed per k
  const float w0 = PI_F / 512.0f;  // exact pow2 scale of pi_f
  float kx = __fmul_rn(jf, w0);
  float kx2 = __fmul_rn(kx, kx);
  float tf0 = (float)tid;
  float tf1 = (float)(tid + 256);
  float a00 = 0.f, a01 = 0.f, a10 = 0.f, a11 = 0.f;
  const float4* mq = (const float4*)msf;  // mq[i] = {m0[2i],m1[2i],m0[2i+1],m1[2i+1]}
#pragma unroll 8
  for (int kloc = 0; kloc < 256; kloc += 2) {
    float4 m = mq[kloc >> 1];
    int k = kbase + kloc;
    float kyA = __fmul_rn((float)k, w0);
    float kyB = __fmul_rn((float)(k + 1), w0);
    float fA = __fsqrt_rn(__fadd_rn(__fmul_rn(kyA, kyA), kx2));
    float fB = __fsqrt_rn(__fadd_rn(__fmul_rn(kyB, kyB), kx2));
    float pA0 = __cosf(__fmul_rn(fA, tf0));  // arg bit-matches ref's f32 F*t
    float pA1 = __cosf(__fmul_rn(fA, tf1));
    float pB0 = __cosf(__fmul_rn(fB, tf0));
    float pB1 = __cosf(__fmul_rn(fB, tf1));
    a00 = fmaf(pA0, m.x, a00); a01 = fmaf(pA0, m.y, a01);
    a10 = fmaf(pA1, m.x, a10); a11 = fmaf(pA1, m.y, a11);
    a00 = fmaf(pB0, m.z, a00); a01 = fmaf(pB0, m.w, a01);
    a10 = fmaf(pB1, m.z, a10); a11 = fmaf(pB1, m.w, a11);
  }
  int base = (kh << 19) + (j << 10);  // half-k partial array
  Vt[base + tid] = a00;
  Vt[base + 256 + tid] = a10;
  Vt[base + 512 + tid] = a01;
  Vt[base + 768 + tid] = a11;
}

// stageC: out[b,t,l] = (1/3) * sum_j Cy[j,l] * (Vt0+Vt1)[j,b,t]; Cy on the fly.
__global__ __launch_bounds__(256, 4) void stageC_kernel(const float* __restrict__ Vt,
                                                        float* __restrict__ out,
                                                        float* __restrict__ partial) {
  __shared__ float vq[2048];  // [j][4] = {b0t0, b1t0, b0t1, b1t1}
  int tpair = blockIdx.x >> 1;
  int lhalf = blockIdx.x & 1;
  int t0 = tpair << 1;
  int tid = threadIdx.x;
#pragma unroll
  for (int r = 0; r < 2; ++r) {
    int j = tid + (r << 8);
    const float* b0 = Vt + (j << 10);
    const float* b1 = b0 + 524288;
    vq[(j << 2) + 0] = b0[t0] + b1[t0];
    vq[(j << 2) + 1] = b0[512 + t0] + b1[512 + t0];
    vq[(j << 2) + 2] = b0[t0 + 1] + b1[t0 + 1];
    vq[(j << 2) + 3] = b0[512 + t0 + 1] + b1[512 + t0 + 1];
  }
  __syncthreads();
  int l = (lhalf << 8) + tid;
  float t1 = __fmul_rn(PI_F, (float)(2 * l + 1));
  float cy0 = __fmul_rn(1.0f / __fsqrt_rn(2048.0f), 2.0f);  // j=0: s0*2*cos(0)
  float4 v0 = *(const float4*)&vq[0];
  float a00 = __fmul_rn(cy0, v0.x);
  float a01 = __fmul_rn(cy0, v0.y);
  float a10 = __fmul_rn(cy0, v0.z);
  float a11 = __fmul_rn(cy0, v0.w);
  for (int j = 1; j < 4; ++j) {
    float arg = __fmul_rn(t1, (float)j) * (1.0f / 1024.0f);
    float c = __fmul_rn(0.0625f, __cosf(arg));
    float4 v = *(const float4*)&vq[j << 2];
    a00 = fmaf(c, v.x, a00);
    a01 = fmaf(c, v.y, a01);
    a10 = fmaf(c, v.z, a10);
    a11 = fmaf(c, v.w, a11);
  }
  for (int j = 4; j < 512; j += 4) {
    float jb = (float)j;
    float c0 = __fmul_rn(0.0625f, __cosf(__fmul_rn(t1, jb) * (1.0f / 1024.0f)));
    float c1 = __fmul_rn(0.0625f, __cosf(__fmul_rn(t1, __fadd_rn(jb, 1.0f)) * (1.0f / 1024.0f)));
    float c2 = __fmul_rn(0.0625f, __cosf(__fmul_rn(t1, __fadd_rn(jb, 2.0f)) * (1.0f / 1024.0f)));
    float c3 = __fmul_rn(0.0625f, __cosf(__fmul_rn(t1, __fadd_rn(jb, 3.0f)) * (1.0f / 1024.0f)));
    float4 va = *(const float4*)&vq[j << 2];
    float4 vb = *(const float4*)&vq[(j + 1) << 2];
    float4 vc = *(const float4*)&vq[(j + 2) << 2];
    float4 vd = *(const float4*)&vq[(j + 3) << 2];
    a00 = fmaf(c0, va.x, a00); a01 = fmaf(c0, va.y, a01);
    a10 = fmaf(c0, va.z, a10); a11 = fmaf(c0, va.w, a11);
    a00 = fmaf(c1, vb.x, a00); a01 = fmaf(c1, vb.y, a01);
    a10 = fmaf(c1, vb.z, a10); a11 = fmaf(c1, vb.w, a11);
    a00 = fmaf(c2, vc.x, a00); a01 = fmaf(c2, vc.y, a01);
    a10 = fmaf(c2, vc.z, a10); a11 = fmaf(c2, vc.w, a11);
    a00 = fmaf(c3, vd.x, a00); a01 = fmaf(c3, vd.y, a01);
    a10 = fmaf(c3, vd.z, a10); a11 = fmaf(c3, vd.w, a11);
  }
  float p00 = a00 / 3.0f, p01 = a01 / 3.0f, p10 = a10 / 3.0f, p11 = a11 / 3.0f;
  out[(t0 << 9) + l] = p00;
  out[((t0 + 1) << 9) + l] = p10;
  out[HALF_N + (t0 << 9) + l] = p01;
  out[HALF_N + ((t0 + 1) << 9) + l] = p11;
  float s0 = p00 + p10, q0 = fmaf(p00, p00, p10 * p10);
  float s1 = p01 + p11, q1 = fmaf(p01, p01, p11 * p11);
  for (int off = 32; off > 0; off >>= 1) {
    s0 += __shfl_down(s0, off);
    q0 += __shfl_down(q0, off);
    s1 += __shfl_down(s1, off);
    q1 += __shfl_down(q1, off);
  }
  __shared__ float red[4][4];
  int wave = tid >> 6;
  if ((tid & 63) == 0) {
    red[wave][0] = s0; red[wave][1] = q0; red[wave][2] = s1; red[wave][3] = q1;
  }
  __syncthreads();
  if (tid == 0) {
    float a0 = 0.f, a1 = 0.f, a2 = 0.f, a3 = 0.f;
    for (int wv = 0; wv < 4; ++wv) {
      a0 += red[wv][0]; a1 += red[wv][1]; a2 += red[wv][2]; a3 += red[wv][3];
    }
    partial[blockIdx.x * 4 + 0] = a0;
    partial[blockIdx.x * 4 + 1] = a1;
    partial[blockIdx.x * 4 + 2] = a2;
    partial[blockIdx.x * 4 + 3] = a3;
  }
}

// Fused stats + noise: redundant partial reduce -> (std0,std1), then threefry noise.
// element i -> threefry2x32(key=(0,42), ctr=(0,i)), bits = o0^o1
__global__ __launch_bounds__(256) void noise_kernel(float* __restrict__ out,
                                                    const float* __restrict__ partial) {
  int tid = threadIdx.x;
  const float4* pq = (const float4*)partial;  // 512 quads {s0,q0,s1,q1}
  float4 pa = pq[tid];
  float4 pb = pq[tid + 256];
  float s0 = pa.x + pb.x, q0 = pa.y + pb.y, s1 = pa.z + pb.z, q1 = pa.w + pb.w;
  for (int off = 32; off > 0; off >>= 1) {
    s0 += __shfl_down(s0, off);
    q0 += __shfl_down(q0, off);
    s1 += __shfl_down(s1, off);
    q1 += __shfl_down(q1, off);
  }
  __shared__ float red[4][4];
  int wave = tid >> 6;
  if ((tid & 63) == 0) {
    red[wave][0] = s0; red[wave][1] = q0; red[wave][2] = s1; red[wave][3] = q1;
  }
  __syncthreads();
  float S = red[0][0] + red[1][0] + red[2][0] + red[3][0];
  float Q = red[0][1] + red[1][1] + red[2][1] + red[3][1];
  float S2 = red[0][2] + red[1][2] + red[2][2] + red[3][2];
  float Q2 = red[0][3] + red[1][3] + red[2][3] + red[3][3];
  const float invN = 1.0f / 262144.0f;
  float m0 = S * invN, m1 = S2 * invN;
  float std0 = __fsqrt_rn(fmaxf(Q * invN - m0 * m0, 0.0f));
  float std1 = __fsqrt_rn(fmaxf(Q2 * invN - m1 * m1, 0.0f));

  int i = blockIdx.x * 256 + tid;  // < 524288
  uint32_t x0 = 0u;
  uint32_t x1 = (uint32_t)i;
  const uint32_t k0 = 0u, k1 = 42u;
  const uint32_t k2 = k0 ^ k1 ^ 0x1BD11BDAu;
  x0 += k0; x1 += k1;
#define QR(r) x0 += x1; x1 = rotl32(x1, r); x1 ^= x0;
  QR(13) QR(15) QR(26) QR(6)
  x0 += k1; x1 += k2 + 1u;
  QR(17) QR(29) QR(16) QR(24)
  x0 += k2; x1 += k0 + 2u;
  QR(13) QR(15) QR(26) QR(6)
  x0 += k0; x1 += k1 + 3u;
  QR(17) QR(29) QR(16) QR(24)
  x0 += k1; x1 += k2 + 4u;
  QR(13) QR(15) QR(26) QR(6)
  x0 += k2; x1 += k0 + 5u;
#undef QR
  uint32_t bits = x0 ^ x1;
  const float lo = __uint_as_float(0xBF7FFFFFu);  // nextafter(-1,0)
  float f = __uint_as_float((bits >> 9) | 0x3F800000u) - 1.0f;
  float u = fmaxf(lo, __fadd_rn(__fmul_rn(f, 2.0f), lo));
  const float sqrt2 = 1.41421356237309515f;
  out[i] += (i < HALF_N ? std0 : std1) * (sqrt2 * erfinv_xla(u));
}

extern "C" void kernel_launch(void* const* d_in, const int* in_sizes, int n_in,
                              void* d_out, int out_size, void* d_ws, size_t ws_size,
                              hipStream_t stream) {
  const float* x = (const float*)d_in[0];
  float* ws = (float*)d_ws;
  float* Vt      = ws;            // 2 x 524288 half-k partials
  float* partial = ws + 1048576;
  float* out = (float*)d_out;

  stageB_kernel<<<1024, 256, 0, stream>>>(x, Vt);
  stageC_kernel<<<512, 256, 0, stream>>>(Vt, out, partial);
  noise_kernel<<<2048, 256, 0, stream>>>(out, partial);
}

// Round 12
// 139.767 us; speedup vs baseline: 1.0707x; 1.0707x over previous
//
#include <hip/hip_runtime.h>
#include <stdint.h>
#include <math.h>

// PhysicsForwardModel: B=2, Nz=Nx=128, Ly=Lx=512.
// out[b,t,l] = (1/3) * sum_j Cy[j,l] * sum_k cos(F[k,j]*t) * a[k] * (Cy[:,:128] x[b] Cy[:,128:256]^T)[k,j]
//              + std_b * N(0,1)  (JAX threefry key=42, partitionable counters, XLA erfinv)
// R12: trans-pipe (v_cos/v_sqrt ~2 lanes/cyc/SIMD) is the wall (R9 vs R11 fit, 84% eff).
// Only the 134M phase-C cos are irreducible; Cy is materialized ONCE (init kernel) and
// phases A/B + stageC read it from L2. Table values bit-match the inline formula
// (all scales are exact pow2 muls), so output is bit-identical to R9.

#define HALF_N 262144  // 512*512 per-batch elements
#define PI_F 3.14159274101257324f

// ws layout (floats): Cy [0..262144) row-major [k][n]; CyT [262144..327680) [i][k] i<128;
//                     Vt [327680..851968) [j][b][t]; partial [851968..854016)

__device__ __forceinline__ uint32_t rotl32(uint32_t v, int r) {
  return (v << r) | (v >> (32 - r));
}

// XLA ErfInv32 (Giles) -- matches reference's lax.erf_inv
__device__ __forceinline__ float erfinv_xla(float x) {
  float w = -log1pf(__fmul_rn(-x, x));
  float p;
  if (w < 5.0f) {
    w = w - 2.5f;
    p = 2.81022636e-08f;
    p = fmaf(p, w, 3.43273939e-07f);
    p = fmaf(p, w, -3.5233877e-06f);
    p = fmaf(p, w, -4.39150654e-06f);
    p = fmaf(p, w, 0.00021858087f);
    p = fmaf(p, w, -0.00125372503f);
    p = fmaf(p, w, -0.00417768164f);
    p = fmaf(p, w, 0.246640727f);
    p = fmaf(p, w, 1.50140941f);
  } else {
    w = __fsqrt_rn(w) - 3.0f;
    p = -0.000200214257f;
    p = fmaf(p, w, 0.000100950558f);
    p = fmaf(p, w, 0.00134934322f);
    p = fmaf(p, w, -0.00367342844f);
    p = fmaf(p, w, 0.00573950773f);
    p = fmaf(p, w, -0.0076224613f);
    p = fmaf(p, w, 0.00943887047f);
    p = fmaf(p, w, 1.00167406f);
    p = fmaf(p, w, 2.83297682f);
  }
  return p * x;
}

// Cy[k,n] = sc(k) * 2 * cos(pi*(2n+1)*k/1024), n2p1 = (float)(2n+1) exact
__device__ __forceinline__ float cy_elem(float n2p1, float kf, float sc) {
  float t1 = __fmul_rn(PI_F, n2p1);
  float arg = __fmul_rn(t1, kf) * (1.0f / 1024.0f);
  return __fmul_rn(sc, __fmul_rn(2.0f, __cosf(arg)));
}

// Materialize Cy [k][n] (262144) and CyT [i][k] = Cy[k][i] for i<128 (65536).
__global__ __launch_bounds__(256) void init_kernel(float* __restrict__ Cy,
                                                   float* __restrict__ CyT) {
  int idx = blockIdx.x * 256 + threadIdx.x;  // < 327680
  const float s0c = 1.0f / __fsqrt_rn(2048.0f);
  if (idx < 262144) {
    int k = idx >> 9, n = idx & 511;
    float sc = (k == 0) ? s0c : 0.03125f;
    Cy[idx] = cy_elem((float)(2 * n + 1), (float)k, sc);
  } else {
    int t = idx - 262144;
    int i = t >> 9, k = t & 511;
    float sc = (k == 0) ? s0c : 0.03125f;
    CyT[t] = cy_elem((float)(2 * i + 1), (float)k, sc);
  }
}

// fusedB, block = j (grid 512, 512 threads):
//   A  (tid<128): cyl[jj] = Cy[j,128+jj]           (table load)
//   A2 (tid<256): us[b*128+i] = sum_jj x[b,i,jj]*cyl[jj]
//   B  (lane=k):  msf[2k+b] = a[k]*sum_i CyT[i][k]*us[b,i]; fs[k]=F[k,j] (sqrt)
//   C  (lane=t):  Vt[j,b,t] = sum_k cos(fs[k]*t) * msf[2k+b]   <- the 134M cos
__global__ __launch_bounds__(512, 4) void stageB_kernel(const float* __restrict__ x,
                                                        const float* __restrict__ Cy,
                                                        const float* __restrict__ CyT,
                                                        float* __restrict__ Vt) {
  __shared__ float cyl[128];
  __shared__ float us[256];
  __shared__ float fs[512];
  __shared__ float msf[1024];
  int j = blockIdx.x;
  int tid = threadIdx.x;
  float jf = (float)j;
  if (tid < 128) cyl[tid] = Cy[(j << 9) + 128 + tid];
  __syncthreads();
  if (tid < 256) {
    int b = tid >> 7, i = tid & 127;
    const float* xr = x + (b * 128 + i) * 128;
    float accA = 0.0f, accB = 0.0f;
    for (int jj = 0; jj < 128; jj += 8) {
      float4 xa = *(const float4*)&xr[jj];
      float4 xb = *(const float4*)&xr[jj + 4];
      float4 ca = *(const float4*)&cyl[jj];
      float4 cb = *(const float4*)&cyl[jj + 4];
      accA = fmaf(xa.x, ca.x, accA); accB = fmaf(xa.y, ca.y, accB);
      accA = fmaf(xa.z, ca.z, accA); accB = fmaf(xa.w, ca.w, accB);
      accA = fmaf(xb.x, cb.x, accA); accB = fmaf(xb.y, cb.y, accB);
      accA = fmaf(xb.z, cb.z, accA); accB = fmaf(xb.w, cb.w, accB);
    }
    us[tid] = accA + accB;
  }
  __syncthreads();
  {
    float kf = (float)tid;
    float a = Cy[tid << 9];  // Cy[k,0] = a[k]
    float acc0 = __fmul_rn(a, us[0]);
    float acc1 = __fmul_rn(a, us[128]);
    float accA0 = 0.f, accA1 = 0.f;
    {
      float c1 = CyT[512 + tid];
      float c2 = CyT[1024 + tid];
      float c3 = CyT[1536 + tid];
      acc0 = fmaf(c1, us[1], acc0);   acc1 = fmaf(c1, us[129], acc1);
      accA0 = fmaf(c2, us[2], accA0); accA1 = fmaf(c2, us[130], accA1);
      acc0 = fmaf(c3, us[3], acc0);   acc1 = fmaf(c3, us[131], acc1);
    }
    for (int i = 4; i < 128; i += 4) {
      float c0 = CyT[(i << 9) + tid];
      float c1 = CyT[((i + 1) << 9) + tid];
      float c2 = CyT[((i + 2) << 9) + tid];
      float c3 = CyT[((i + 3) << 9) + tid];
      float4 u0 = *(const float4*)&us[i];
      float4 u1 = *(const float4*)&us[128 + i];
      acc0 = fmaf(c0, u0.x, acc0);   acc1 = fmaf(c0, u1.x, acc1);
      accA0 = fmaf(c1, u0.y, accA0); accA1 = fmaf(c1, u1.y, accA1);
      acc0 = fmaf(c2, u0.z, acc0);   acc1 = fmaf(c2, u1.z, acc1);
      accA0 = fmaf(c3, u0.w, accA0); accA1 = fmaf(c3, u1.w, accA1);
    }
    acc0 += accA0;
    acc1 += accA1;
    const float w0 = PI_F / 512.0f;  // exact pow2 scale of pi_f
    float ky = __fmul_rn(kf, w0);
    float kx = __fmul_rn(jf, w0);
    fs[tid] = __fsqrt_rn(__fadd_rn(__fmul_rn(ky, ky), __fmul_rn(kx, kx)));
    msf[2 * tid] = __fmul_rn(a, acc0);
    msf[2 * tid + 1] = __fmul_rn(a, acc1);
  }
  __syncthreads();
  float tf = (float)tid;
  float acc0 = 0.f, acc1 = 0.f, acc2 = 0.f, acc3 = 0.f;
  for (int k0 = 0; k0 < 512; k0 += 8) {
    float4 f0 = *(const float4*)&fs[k0];
    float4 f1 = *(const float4*)&fs[k0 + 4];
    float4 m0 = *(const float4*)&msf[2 * k0];
    float4 m1 = *(const float4*)&msf[2 * k0 + 4];
    float4 m2 = *(const float4*)&msf[2 * k0 + 8];
    float4 m3 = *(const float4*)&msf[2 * k0 + 12];
    float ph0 = __cosf(__fmul_rn(f0.x, tf));  // arg bit-matches ref's f32 F*t
    float ph1 = __cosf(__fmul_rn(f0.y, tf));
    float ph2 = __cosf(__fmul_rn(f0.z, tf));
    float ph3 = __cosf(__fmul_rn(f0.w, tf));
    float ph4 = __cosf(__fmul_rn(f1.x, tf));
    float ph5 = __cosf(__fmul_rn(f1.y, tf));
    float ph6 = __cosf(__fmul_rn(f1.z, tf));
    float ph7 = __cosf(__fmul_rn(f1.w, tf));
    acc0 = fmaf(ph0, m0.x, acc0); acc1 = fmaf(ph0, m0.y, acc1);
    acc2 = fmaf(ph1, m0.z, acc2); acc3 = fmaf(ph1, m0.w, acc3);
    acc0 = fmaf(ph2, m1.x, acc0); acc1 = fmaf(ph2, m1.y, acc1);
    acc2 = fmaf(ph3, m1.z, acc2); acc3 = fmaf(ph3, m1.w, acc3);
    acc0 = fmaf(ph4, m2.x, acc0); acc1 = fmaf(ph4, m2.y, acc1);
    acc2 = fmaf(ph5, m2.z, acc2); acc3 = fmaf(ph5, m2.w, acc3);
    acc0 = fmaf(ph6, m3.x, acc0); acc1 = fmaf(ph6, m3.y, acc1);
    acc2 = fmaf(ph7, m3.z, acc2); acc3 = fmaf(ph7, m3.w, acc3);
  }
  Vt[(j << 10) + tid] = acc0 + acc2;
  Vt[(j << 10) + 512 + tid] = acc1 + acc3;
}

// stageC: out[b,t,l] = (1/3) * sum_j Cy[j,l] * Vt[j,b,t]; Cy from table (coalesced).
__global__ __launch_bounds__(256, 4) void stageC_kernel(const float* __restrict__ Cy,
                                                        const float* __restrict__ Vt,
                                                        float* __restrict__ out,
                                                        float* __restrict__ partial) {
  __shared__ float vq[2048];  // [j][4] = {b0t0, b1t0, b0t1, b1t1}
  int tpair = blockIdx.x >> 1;
  int lhalf = blockIdx.x & 1;
  int t0 = tpair << 1;
  int tid = threadIdx.x;
#pragma unroll
  for (int r = 0; r < 2; ++r) {
    int j = tid + (r << 8);
    const float* base = Vt + (j << 10);
    vq[(j << 2) + 0] = base[t0];
    vq[(j << 2) + 1] = base[512 + t0];
    vq[(j << 2) + 2] = base[t0 + 1];
    vq[(j << 2) + 3] = base[512 + t0 + 1];
  }
  __syncthreads();
  int l = (lhalf << 8) + tid;
  float a00 = 0.f, a01 = 0.f, a10 = 0.f, a11 = 0.f;
  for (int j = 0; j < 512; j += 4) {
    float c0 = Cy[(j << 9) + l];
    float c1 = Cy[((j + 1) << 9) + l];
    float c2 = Cy[((j + 2) << 9) + l];
    float c3 = Cy[((j + 3) << 9) + l];
    float4 va = *(const float4*)&vq[j << 2];
    float4 vb = *(const float4*)&vq[(j + 1) << 2];
    float4 vc = *(const float4*)&vq[(j + 2) << 2];
    float4 vd = *(const float4*)&vq[(j + 3) << 2];
    a00 = fmaf(c0, va.x, a00); a01 = fmaf(c0, va.y, a01);
    a10 = fmaf(c0, va.z, a10); a11 = fmaf(c0, va.w, a11);
    a00 = fmaf(c1, vb.x, a00); a01 = fmaf(c1, vb.y, a01);
    a10 = fmaf(c1, vb.z, a10); a11 = fmaf(c1, vb.w, a11);
    a00 = fmaf(c2, vc.x, a00); a01 = fmaf(c2, vc.y, a01);
    a10 = fmaf(c2, vc.z, a10); a11 = fmaf(c2, vc.w, a11);
    a00 = fmaf(c3, vd.x, a00); a01 = fmaf(c3, vd.y, a01);
    a10 = fmaf(c3, vd.z, a10); a11 = fmaf(c3, vd.w, a11);
  }
  float p00 = a00 / 3.0f, p01 = a01 / 3.0f, p10 = a10 / 3.0f, p11 = a11 / 3.0f;
  out[(t0 << 9) + l] = p00;
  out[((t0 + 1) << 9) + l] = p10;
  out[HALF_N + (t0 << 9) + l] = p01;
  out[HALF_N + ((t0 + 1) << 9) + l] = p11;
  float s0 = p00 + p10, q0 = fmaf(p00, p00, p10 * p10);
  float s1 = p01 + p11, q1 = fmaf(p01, p01, p11 * p11);
  for (int off = 32; off > 0; off >>= 1) {
    s0 += __shfl_down(s0, off);
    q0 += __shfl_down(q0, off);
    s1 += __shfl_down(s1, off);
    q1 += __shfl_down(q1, off);
  }
  __shared__ float red[4][4];
  int wave = tid >> 6;
  if ((tid & 63) == 0) {
    red[wave][0] = s0; red[wave][1] = q0; red[wave][2] = s1; red[wave][3] = q1;
  }
  __syncthreads();
  if (tid == 0) {
    float a0 = 0.f, a1 = 0.f, a2 = 0.f, a3 = 0.f;
    for (int wv = 0; wv < 4; ++wv) {
      a0 += red[wv][0]; a1 += red[wv][1]; a2 += red[wv][2]; a3 += red[wv][3];
    }
    partial[blockIdx.x * 4 + 0] = a0;
    partial[blockIdx.x * 4 + 1] = a1;
    partial[blockIdx.x * 4 + 2] = a2;
    partial[blockIdx.x * 4 + 3] = a3;
  }
}

// Fused stats + noise: redundant partial reduce -> (std0,std1), then threefry noise.
// element i -> threefry2x32(key=(0,42), ctr=(0,i)), bits = o0^o1
__global__ __launch_bounds__(256) void noise_kernel(float* __restrict__ out,
                                                    const float* __restrict__ partial) {
  int tid = threadIdx.x;
  const float4* pq = (const float4*)partial;  // 512 quads {s0,q0,s1,q1}
  float4 pa = pq[tid];
  float4 pb = pq[tid + 256];
  float s0 = pa.x + pb.x, q0 = pa.y + pb.y, s1 = pa.z + pb.z, q1 = pa.w + pb.w;
  for (int off = 32; off > 0; off >>= 1) {
    s0 += __shfl_down(s0, off);
    q0 += __shfl_down(q0, off);
    s1 += __shfl_down(s1, off);
    q1 += __shfl_down(q1, off);
  }
  __shared__ float red[4][4];
  int wave = tid >> 6;
  if ((tid & 63) == 0) {
    red[wave][0] = s0; red[wave][1] = q0; red[wave][2] = s1; red[wave][3] = q1;
  }
  __syncthreads();
  float S = red[0][0] + red[1][0] + red[2][0] + red[3][0];
  float Q = red[0][1] + red[1][1] + red[2][1] + red[3][1];
  float S2 = red[0][2] + red[1][2] + red[2][2] + red[3][2];
  float Q2 = red[0][3] + red[1][3] + red[2][3] + red[3][3];
  const float invN = 1.0f / 262144.0f;
  float m0 = S * invN, m1 = S2 * invN;
  float std0 = __fsqrt_rn(fmaxf(Q * invN - m0 * m0, 0.0f));
  float std1 = __fsqrt_rn(fmaxf(Q2 * invN - m1 * m1, 0.0f));

  int i = blockIdx.x * 256 + tid;  // < 524288
  uint32_t x0 = 0u;
  uint32_t x1 = (uint32_t)i;
  const uint32_t k0 = 0u, k1 = 42u;
  const uint32_t k2 = k0 ^ k1 ^ 0x1BD11BDAu;
  x0 += k0; x1 += k1;
#define QR(r) x0 += x1; x1 = rotl32(x1, r); x1 ^= x0;
  QR(13) QR(15) QR(26) QR(6)
  x0 += k1; x1 += k2 + 1u;
  QR(17) QR(29) QR(16) QR(24)
  x0 += k2; x1 += k0 + 2u;
  QR(13) QR(15) QR(26) QR(6)
  x0 += k0; x1 += k1 + 3u;
  QR(17) QR(29) QR(16) QR(24)
  x0 += k1; x1 += k2 + 4u;
  QR(13) QR(15) QR(26) QR(6)
  x0 += k2; x1 += k0 + 5u;
#undef QR
  uint32_t bits = x0 ^ x1;
  const float lo = __uint_as_float(0xBF7FFFFFu);  // nextafter(-1,0)
  float f = __uint_as_float((bits >> 9) | 0x3F800000u) - 1.0f;
  float u = fmaxf(lo, __fadd_rn(__fmul_rn(f, 2.0f), lo));
  const float sqrt2 = 1.41421356237309515f;
  out[i] += (i < HALF_N ? std0 : std1) * (sqrt2 * erfinv_xla(u));
}

extern "C" void kernel_launch(void* const* d_in, const int* in_sizes, int n_in,
                              void* d_out, int out_size, void* d_ws, size_t ws_size,
                              hipStream_t stream) {
  const float* x = (const float*)d_in[0];
  float* ws = (float*)d_ws;
  float* Cy      = ws;
  float* CyT     = ws + 262144;
  float* Vt      = ws + 327680;
  float* partial = ws + 851968;
  float* out = (float*)d_out;

  init_kernel<<<1280, 256, 0, stream>>>(Cy, CyT);
  stageB_kernel<<<512, 512, 0, stream>>>(x, Cy, CyT, Vt);
  stageC_kernel<<<512, 256, 0, stream>>>(Cy, Vt, out, partial);
  noise_kernel<<<2048, 256, 0, stream>>>(out, partial);
}